// Round 3
// baseline (305.873 us; speedup 1.0000x reference)
//
#include <hip/hip_runtime.h>
#include <hip/hip_fp16.h>

typedef _Float16 f16;
typedef _Float16 f16x4_t __attribute__((ext_vector_type(4)));
typedef _Float16 f16x8_t __attribute__((ext_vector_type(8)));
typedef float    f32x4_t __attribute__((ext_vector_type(4)));

#define NB  4
#define NC  256
#define NH  256
#define NW  256

// ---------------- kernel 1: convert weights (f,g,h) to f16, row-major [cout][ch] ----
__global__ __launch_bounds__(256) void k_convert_w(
    const float* __restrict__ f_w, const float* __restrict__ g_w,
    const float* __restrict__ h_w, f16* __restrict__ wf)
{
    int id = blockIdx.x * 256 + threadIdx.x;   // 0 .. 131071  (512*256)
    int cout = id >> 8;
    float v;
    if (cout < 128)       v = f_w[id];
    else if (cout < 256)  v = g_w[id - 128*256];
    else                  v = h_w[id - 256*256];
    wf[id] = (f16)v;
}

// ---------------- kernel 2: fused conv1x1 (512 couts) + 16x16 maxpool ----------------
// 256 blocks x 512 threads (8 waves), 4 windows/block, 32 stages of 32 pos.
// Wave w covers couts w*64..w*64+63 (n=4 16-frags): waves 0-3 = f,g (hi/lo 2-pass),
// waves 4-7 = h (1-pass). Weights persistent in VGPRs (128/wave).
// LDS identity fragment layout: element (pos 0..31, ch 0..255) of a stage at
//   byte = (m*8+k)<<10 + lane*16 + (ch&7)*2,  m=pos>>4, k=ch>>5,
//   lane = (pos&15) | (((ch>>3)&3)<<4)
// => ds_read_b128 A-fragments are lane-linear (byte = lane*16): conflict-free.
// Staging: thread owns dx strided by 4 (q, q+4, q+8, q+12) x 4 consecutive ch:
// b64 f16x4 writes; 16-lane write phases cover 8 distinct 8B granules (2-way, free).
__global__ __launch_bounds__(512, 2) void k_pooled_conv(
    const float* __restrict__ x, const f16* __restrict__ wf,
    const float* __restrict__ f_b, const float* __restrict__ g_b,
    const float* __restrict__ h_b,
    float* __restrict__ pooled_fg,   // [B][256][256]
    float* __restrict__ pooledT_h)   // [B][256][256]
{
    __shared__ __align__(16) char smem[65536];  // 2 buffers x (16KB hi + 16KB lo)

    const int t    = threadIdx.x;
    const int wave = t >> 6;
    const int lane = t & 63;
    const int l15  = lane & 15;
    const int lg   = lane >> 4;
    const bool isfg = (wave < 4);
    const int coutbase = wave * 64;   // 0..192 (fg) / 256..448 (h)

    // ---- persistent weight fragments: 4 cout-frags x 8 k-steps ----
    f16x8_t bfrag[4][8];
    #pragma unroll
    for (int n = 0; n < 4; n++) {
        const f16* wr = wf + (coutbase + n*16 + l15) * 256 + lg*8;
        #pragma unroll
        for (int k = 0; k < 8; k++)
            bfrag[n][k] = *(const f16x8_t*)(wr + k*32);
    }
    float biasv[4];
    #pragma unroll
    for (int n = 0; n < 4; n++) {
        int c = coutbase + n*16 + l15;
        biasv[n] = (c < 128) ? f_b[c] : (c < 256) ? g_b[c - 128] : h_b[c - 256];
    }

    // ---- staging coords ----
    const int q   = t & 3;            // dx low
    const int dyl = (t >> 2) & 1;     // row within stage pair
    const int c0  = (t >> 3) * 4;     // 0..252, 4 consecutive ch
    unsigned woff[4];
    #pragma unroll
    for (int w = 0; w < 4; w++) {
        int dx = q + 4*w;
        unsigned lslot = (unsigned)(dx | (((c0 >> 3) & 3) << 4));
        woff[w] = ((unsigned)(dyl*8 + (c0 >> 5)) << 10) + lslot*16u + (unsigned)((c0 & 4) * 2);
    }

    const int bid   = blockIdx.x;
    const int b     = bid >> 6;
    const int wbase = bid * 4;
    const float* xb = x + (size_t)b * (256u * 65536u);

    float vmax[4] = {-3.0e38f, -3.0e38f, -3.0e38f, -3.0e38f};

    auto loadst = [&](int gsd, float* r) {
        int win = wbase + (gsd >> 3);
        int s   = gsd & 7;
        int wi = (win >> 4) & 15, wj = win & 15;
        const float* src = xb + (size_t)c0 * 65536u
                         + (unsigned)((wi*16 + s*2 + dyl) * 256 + wj*16 + q);
        #pragma unroll
        for (int cc = 0; cc < 4; cc++)
            #pragma unroll
            for (int w = 0; w < 4; w++)
                r[cc*4 + w] = src[(unsigned)cc * 65536u + (unsigned)w * 4u];
    };
    auto writest = [&](const float* r, int buf) {
        char* base = smem + buf * 32768;
        #pragma unroll
        for (int w = 0; w < 4; w++) {
            f16x4_t hv, lv;
            #pragma unroll
            for (int cc = 0; cc < 4; cc++) {
                float v = r[cc*4 + w];
                f16 h = (f16)v;
                hv[cc] = h;
                lv[cc] = (f16)(v - (float)h);
            }
            *(f16x4_t*)(base + woff[w])         = hv;
            *(f16x4_t*)(base + 16384 + woff[w]) = lv;
        }
    };
    auto mfmast = [&](int buf) {
        const char* base = smem + buf * 32768 + lane * 16;
        #pragma unroll
        for (int m = 0; m < 2; m++) {
            f32x4_t acc[4] = {{0.f,0.f,0.f,0.f},{0.f,0.f,0.f,0.f},
                              {0.f,0.f,0.f,0.f},{0.f,0.f,0.f,0.f}};
            #pragma unroll
            for (int k = 0; k < 8; k++) {
                const char* p = base + ((m*8 + k) << 10);
                f16x8_t ah = *(const f16x8_t*)p;
                #pragma unroll
                for (int n = 0; n < 4; n++)
                    acc[n] = __builtin_amdgcn_mfma_f32_16x16x32_f16(ah, bfrag[n][k], acc[n], 0,0,0);
                if (isfg) {
                    f16x8_t al = *(const f16x8_t*)(p + 16384);
                    #pragma unroll
                    for (int n = 0; n < 4; n++)
                        acc[n] = __builtin_amdgcn_mfma_f32_16x16x32_f16(al, bfrag[n][k], acc[n], 0,0,0);
                }
            }
            #pragma unroll
            for (int n = 0; n < 4; n++)
                #pragma unroll
                for (int r = 0; r < 4; r++)
                    vmax[n] = fmaxf(vmax[n], acc[n][r]);
        }
    };
    auto finalize = [&](int win) {
        int wn = win & 255;
        #pragma unroll
        for (int n = 0; n < 4; n++) {
            float v = vmax[n];
            v = fmaxf(v, __shfl_xor(v, 16, 64));
            v = fmaxf(v, __shfl_xor(v, 32, 64));
            if (lane < 16) {
                float val = v + biasv[n];
                int c = coutbase + n*16 + lane;
                if (isfg) pooled_fg[((b*256 + c)  << 8) + wn] = val;
                else      pooledT_h[((b*256 + wn) << 8) + (c - 256)] = val;
            }
            vmax[n] = -3.0e38f;
        }
    };

    // ---- pipeline: 32 global stages (4 windows x 8 stages of 2 rows) ----
    float rA[16], rB[16];
    loadst(0, rA);
    writest(rA, 0);
    loadst(1, rB);
    __syncthreads();

    #pragma unroll 1
    for (int gs = 0; gs < 32; gs += 2) {
        if (gs + 2 < 32) loadst(gs + 2, rA);
        writest(rB, 1);
        mfmast(0);
        __syncthreads();
        if (gs + 3 < 32) loadst(gs + 3, rB);
        if (gs + 2 < 32) writest(rA, 0);
        mfmast(1);
        if ((gs & 7) == 6) finalize(wbase + (gs >> 3));
        __syncthreads();
    }
}

// ---------------- kernel 3: dots + softmax + PV (all fp32) ----------------
__global__ __launch_bounds__(256) void k_attn(
    const float* __restrict__ pooled_fg, const float* __restrict__ pooledT_h,
    float* __restrict__ attnout)   // [B][256][256]
{
    __shared__ float red[4];
    __shared__ float p_lds[256];
    const int blk = blockIdx.x;
    const int b = blk >> 8;
    const int q = blk & 255;
    const int t = threadIdx.x;

    const float* fv = pooled_fg + ((b*256) << 8) + q;         // fv[c][q]
    const float* gv = pooled_fg + ((b*256 + 128) << 8) + t;   // gv[c][t]

    float s = 0.f;
    #pragma unroll 8
    for (int c = 0; c < 128; c++)
        s += fv[c << 8] * gv[c << 8];

    float m = s;
    #pragma unroll
    for (int o = 1; o < 64; o <<= 1) m = fmaxf(m, __shfl_xor(m, o, 64));
    if ((t & 63) == 0) red[t >> 6] = m;
    __syncthreads();
    m = fmaxf(fmaxf(red[0], red[1]), fmaxf(red[2], red[3]));
    __syncthreads();

    float p = expf(s - m);
    float sum = p;
    #pragma unroll
    for (int o = 1; o < 64; o <<= 1) sum += __shfl_xor(sum, o, 64);
    if ((t & 63) == 0) red[t >> 6] = sum;
    __syncthreads();
    sum = red[0] + red[1] + red[2] + red[3];
    p /= sum;
    p_lds[t] = p;
    __syncthreads();

    const float* hv = pooledT_h + (b << 16) + t;
    float acc = 0.f;
    #pragma unroll 8
    for (int k = 0; k < 256; k++)
        acc += p_lds[k] * hv[k << 8];
    attnout[((b*256 + t) << 8) + q] = acc;
}

// ---------------- kernel 4: bilinear 16x upsample (half-pixel, edge-clamped) + x ----
__global__ __launch_bounds__(256) void k_upsample_add(
    const float* __restrict__ x, const float* __restrict__ attnout,
    float* __restrict__ out)
{
    __shared__ float L[256];
    const int blk = blockIdx.x;            // b*256 + c
    const int t = threadIdx.x;
    L[t] = attnout[(blk << 8) + t];
    __syncthreads();
    const float* xp = x   + (size_t)blk * 65536;
    float*       op = out + (size_t)blk * 65536;

    const int x4 = (t & 63) << 2;
    const int yo = t >> 6;
    float fxv[4]; int x0v[4], x1v[4];
    #pragma unroll
    for (int e = 0; e < 4; e++) {
        float sx  = (x4 + e + 0.5f) * 0.0625f - 0.5f;
        float x0f = floorf(sx);
        fxv[e] = sx - x0f;
        int ix0 = (int)x0f;
        x0v[e] = min(15, max(0, ix0));
        x1v[e] = min(15, max(0, ix0 + 1));
    }
    for (int it = 0; it < 64; it++) {
        int y = it*4 + yo;
        float sy  = (y + 0.5f) * 0.0625f - 0.5f;
        float y0f = floorf(sy);
        float fy  = sy - y0f;
        int iy0 = (int)y0f;
        int y0 = min(15, max(0, iy0));
        int y1 = min(15, max(0, iy0 + 1));
        const float* Ly0 = L + y0*16;
        const float* Ly1 = L + y1*16;
        float4 xin = *(const float4*)(xp + y*256 + x4);
        float o[4]; const float* xe = (const float*)&xin;
        #pragma unroll
        for (int e = 0; e < 4; e++) {
            float top = Ly0[x0v[e]] + fxv[e] * (Ly0[x1v[e]] - Ly0[x0v[e]]);
            float bot = Ly1[x0v[e]] + fxv[e] * (Ly1[x1v[e]] - Ly1[x0v[e]]);
            o[e] = top + fy * (bot - top) + xe[e];
        }
        float4 ov = make_float4(o[0], o[1], o[2], o[3]);
        *(float4*)(op + y*256 + x4) = ov;
    }
}

extern "C" void kernel_launch(void* const* d_in, const int* in_sizes, int n_in,
                              void* d_out, int out_size, void* d_ws, size_t ws_size,
                              hipStream_t stream)
{
    const float* x   = (const float*)d_in[0];
    const float* f_w = (const float*)d_in[1];
    const float* f_b = (const float*)d_in[2];
    const float* g_w = (const float*)d_in[3];
    const float* g_b = (const float*)d_in[4];
    const float* h_w = (const float*)d_in[5];
    const float* h_b = (const float*)d_in[6];
    float* out = (float*)d_out;

    char* ws = (char*)d_ws;
    f16*   wf        = (f16*)ws;                              // 256 KB
    float* pooled_fg = (float*)(ws + (256<<10));              // 1 MB  [B][256][256]
    float* pooledT_h = (float*)(ws + (256<<10) + (1<<20));    // 1 MB  [B][256][256]
    float* attnout   = (float*)(ws + (256<<10) + (2<<20));    // 1 MB  [B][256][256]

    k_convert_w   <<<512, 256, 0, stream>>>(f_w, g_w, h_w, wf);
    k_pooled_conv <<<256, 512, 0, stream>>>(x, wf, f_b, g_b, h_b, pooled_fg, pooledT_h);
    k_attn        <<<1024, 256, 0, stream>>>(pooled_fg, pooledT_h, attnout);
    k_upsample_add<<<1024, 256, 0, stream>>>(x, attnout, out);
}

// Round 4
// 296.126 us; speedup vs baseline: 1.0329x; 1.0329x over previous
//
#include <hip/hip_runtime.h>
#include <hip/hip_fp16.h>

typedef _Float16 f16;
typedef _Float16 f16x4_t __attribute__((ext_vector_type(4)));
typedef _Float16 f16x8_t __attribute__((ext_vector_type(8)));
typedef float    f32x4_t __attribute__((ext_vector_type(4)));

#define NB  4
#define NC  256
#define NH  256
#define NW  256

// ---------------- kernel 1: convert weights (f,g,h) to f16, row-major [cout][ch] ----
__global__ __launch_bounds__(256) void k_convert_w(
    const float* __restrict__ f_w, const float* __restrict__ g_w,
    const float* __restrict__ h_w, f16* __restrict__ wf)
{
    int id = blockIdx.x * 256 + threadIdx.x;   // 0 .. 131071  (512*256)
    int cout = id >> 8;
    float v;
    if (cout < 128)       v = f_w[id];
    else if (cout < 256)  v = g_w[id - 128*256];
    else                  v = h_w[id - 256*256];
    wf[id] = (f16)v;
}

// ---------------- kernel 2: fused conv1x1 (512 couts) + 16x16 maxpool ----------------
// 256 blocks x 1024 threads (16 waves, 4/SIMD), 4 windows/block, 32 stages of 32 pos.
// Wave w: 32 couts (n=2). Waves 0-7 = f,g (hi/lo 2-pass), waves 8-15 = h (1-pass).
// Weights persistent: bfrag[2][8] = 64 VGPR. __launch_bounds__(1024,4) caps at 128.
// LDS identity layout: element (pos, ch) at byte = page<<10 + slot*16 + (ch&7)*2,
//   page = (pos>>4)*8 + (ch>>5), slot = (pos&15) | (((ch>>3)&3)<<4)
// -> A-frag ds_read_b128 at lane*16 within page: lane-linear, conflict-free.
// Staging: thread owns 1 dx x 8 consecutive ch -> single f16x8 b128 write (hi + lo).
__global__ __launch_bounds__(1024, 4) void k_pooled_conv(
    const float* __restrict__ x, const f16* __restrict__ wf,
    const float* __restrict__ f_b, const float* __restrict__ g_b,
    const float* __restrict__ h_b,
    float* __restrict__ pooled_fg,   // [B][256][256]
    float* __restrict__ pooledT_h)   // [B][256][256]
{
    __shared__ __align__(16) char smem[65536];  // 2 buffers x (16KB hi + 16KB lo)

    const int t    = threadIdx.x;
    const int wave = t >> 6;
    const int lane = t & 63;
    const int l15  = lane & 15;
    const int lg   = lane >> 4;
    const bool isfg = (wave < 8);
    const int coutbase = isfg ? wave * 32 : 256 + (wave - 8) * 32;

    // ---- persistent weight fragments: 2 cout-frags x 8 k-steps (64 VGPR) ----
    f16x8_t bfrag[2][8];
    #pragma unroll
    for (int n = 0; n < 2; n++) {
        const f16* wr = wf + (coutbase + n*16 + l15) * 256 + lg*8;
        #pragma unroll
        for (int k = 0; k < 8; k++)
            bfrag[n][k] = *(const f16x8_t*)(wr + k*32);
    }
    float biasv[2];
    #pragma unroll
    for (int n = 0; n < 2; n++) {
        int c = coutbase + n*16 + l15;
        biasv[n] = (c < 128) ? f_b[c] : (c < 256) ? g_b[c - 128] : h_b[c - 256];
    }

    // ---- staging coords: thread owns 1 dx x 8 consecutive ch ----
    const int dx  = t & 15;
    const int dyl = (t >> 4) & 1;
    const int c8  = (t >> 5) * 8;     // 0..248
    const unsigned page = (unsigned)(dyl*8 + (c8 >> 5));
    const unsigned slot = (unsigned)(dx | (((c8 >> 3) & 3) << 4));
    const unsigned woff = (page << 10) + slot * 16u;

    const int bid   = blockIdx.x;
    const int b     = bid >> 6;
    const int wbase = bid * 4;
    const float* xb = x + (size_t)b * (256u * 65536u);

    float vmax[2] = {-3.0e38f, -3.0e38f};

    auto loadst = [&](int gsd, float* r) {
        int win = wbase + (gsd >> 3);
        int s   = gsd & 7;
        int wi = (win >> 4) & 15, wj = win & 15;
        const float* src = xb + (size_t)c8 * 65536u
                         + (unsigned)((wi*16 + s*2 + dyl) * 256 + wj*16 + dx);
        #pragma unroll
        for (int cc = 0; cc < 8; cc++)
            r[cc] = src[(unsigned)cc * 65536u];
    };
    auto writest = [&](const float* r, int buf) {
        char* base = smem + buf * 32768;
        f16x8_t hv, lv;
        #pragma unroll
        for (int cc = 0; cc < 8; cc++) {
            float v = r[cc];
            f16 h = (f16)v;
            hv[cc] = h;
            lv[cc] = (f16)(v - (float)h);
        }
        *(f16x8_t*)(base + woff)         = hv;
        *(f16x8_t*)(base + 16384 + woff) = lv;
    };
    auto mfmast = [&](int buf) {
        const char* base = smem + buf * 32768 + lane * 16;
        #pragma unroll
        for (int m = 0; m < 2; m++) {
            f32x4_t acc0 = {0.f,0.f,0.f,0.f}, acc1 = {0.f,0.f,0.f,0.f};
            #pragma unroll
            for (int k = 0; k < 8; k++) {
                const char* p = base + ((m*8 + k) << 10);
                f16x8_t ah = *(const f16x8_t*)p;
                acc0 = __builtin_amdgcn_mfma_f32_16x16x32_f16(ah, bfrag[0][k], acc0, 0,0,0);
                acc1 = __builtin_amdgcn_mfma_f32_16x16x32_f16(ah, bfrag[1][k], acc1, 0,0,0);
                if (isfg) {
                    f16x8_t al = *(const f16x8_t*)(p + 16384);
                    acc0 = __builtin_amdgcn_mfma_f32_16x16x32_f16(al, bfrag[0][k], acc0, 0,0,0);
                    acc1 = __builtin_amdgcn_mfma_f32_16x16x32_f16(al, bfrag[1][k], acc1, 0,0,0);
                }
            }
            #pragma unroll
            for (int r = 0; r < 4; r++) {
                vmax[0] = fmaxf(vmax[0], acc0[r]);
                vmax[1] = fmaxf(vmax[1], acc1[r]);
            }
        }
    };
    auto finalize = [&](int win) {
        int wn = win & 255;
        #pragma unroll
        for (int n = 0; n < 2; n++) {
            float v = vmax[n];
            v = fmaxf(v, __shfl_xor(v, 16, 64));
            v = fmaxf(v, __shfl_xor(v, 32, 64));
            if (lane < 16) {
                float val = v + biasv[n];
                int c = coutbase + n*16 + lane;
                if (isfg) pooled_fg[((b*256 + c)  << 8) + wn] = val;
                else      pooledT_h[((b*256 + wn) << 8) + (c - 256)] = val;
            }
            vmax[n] = -3.0e38f;
        }
    };

    // ---- pipeline: 32 global stages (4 windows x 8 stages of 2 rows) ----
    float rA[8], rB[8];
    loadst(0, rA);
    writest(rA, 0);
    loadst(1, rB);
    __syncthreads();

    #pragma unroll 1
    for (int gs = 0; gs < 32; gs += 2) {
        if (gs + 2 < 32) loadst(gs + 2, rA);
        writest(rB, 1);
        mfmast(0);
        __syncthreads();
        if (gs + 3 < 32) loadst(gs + 3, rB);
        if (gs + 2 < 32) writest(rA, 0);
        mfmast(1);
        if ((gs & 7) == 6) finalize(wbase + (gs >> 3));
        __syncthreads();
    }
}

// ---------------- kernel 3: dots + softmax + PV (all fp32) ----------------
__global__ __launch_bounds__(256) void k_attn(
    const float* __restrict__ pooled_fg, const float* __restrict__ pooledT_h,
    float* __restrict__ attnout)   // [B][256][256]
{
    __shared__ float red[4];
    __shared__ float p_lds[256];
    const int blk = blockIdx.x;
    const int b = blk >> 8;
    const int q = blk & 255;
    const int t = threadIdx.x;

    const float* fv = pooled_fg + ((b*256) << 8) + q;         // fv[c][q]
    const float* gv = pooled_fg + ((b*256 + 128) << 8) + t;   // gv[c][t]

    float s = 0.f;
    #pragma unroll 8
    for (int c = 0; c < 128; c++)
        s += fv[c << 8] * gv[c << 8];

    float m = s;
    #pragma unroll
    for (int o = 1; o < 64; o <<= 1) m = fmaxf(m, __shfl_xor(m, o, 64));
    if ((t & 63) == 0) red[t >> 6] = m;
    __syncthreads();
    m = fmaxf(fmaxf(red[0], red[1]), fmaxf(red[2], red[3]));
    __syncthreads();

    float p = expf(s - m);
    float sum = p;
    #pragma unroll
    for (int o = 1; o < 64; o <<= 1) sum += __shfl_xor(sum, o, 64);
    if ((t & 63) == 0) red[t >> 6] = sum;
    __syncthreads();
    sum = red[0] + red[1] + red[2] + red[3];
    p /= sum;
    p_lds[t] = p;
    __syncthreads();

    const float* hv = pooledT_h + (b << 16) + t;
    float acc = 0.f;
    #pragma unroll 8
    for (int k = 0; k < 256; k++)
        acc += p_lds[k] * hv[k << 8];
    attnout[((b*256 + t) << 8) + q] = acc;
}

// ---------------- kernel 4: bilinear 16x upsample (half-pixel, edge-clamped) + x ----
__global__ __launch_bounds__(256) void k_upsample_add(
    const float* __restrict__ x, const float* __restrict__ attnout,
    float* __restrict__ out)
{
    __shared__ float L[256];
    const int blk = blockIdx.x;            // b*256 + c
    const int t = threadIdx.x;
    L[t] = attnout[(blk << 8) + t];
    __syncthreads();
    const float* xp = x   + (size_t)blk * 65536;
    float*       op = out + (size_t)blk * 65536;

    const int x4 = (t & 63) << 2;
    const int yo = t >> 6;
    float fxv[4]; int x0v[4], x1v[4];
    #pragma unroll
    for (int e = 0; e < 4; e++) {
        float sx  = (x4 + e + 0.5f) * 0.0625f - 0.5f;
        float x0f = floorf(sx);
        fxv[e] = sx - x0f;
        int ix0 = (int)x0f;
        x0v[e] = min(15, max(0, ix0));
        x1v[e] = min(15, max(0, ix0 + 1));
    }
    for (int it = 0; it < 64; it++) {
        int y = it*4 + yo;
        float sy  = (y + 0.5f) * 0.0625f - 0.5f;
        float y0f = floorf(sy);
        float fy  = sy - y0f;
        int iy0 = (int)y0f;
        int y0 = min(15, max(0, iy0));
        int y1 = min(15, max(0, iy0 + 1));
        const float* Ly0 = L + y0*16;
        const float* Ly1 = L + y1*16;
        float4 xin = *(const float4*)(xp + y*256 + x4);
        float o[4]; const float* xe = (const float*)&xin;
        #pragma unroll
        for (int e = 0; e < 4; e++) {
            float top = Ly0[x0v[e]] + fxv[e] * (Ly0[x1v[e]] - Ly0[x0v[e]]);
            float bot = Ly1[x0v[e]] + fxv[e] * (Ly1[x1v[e]] - Ly1[x0v[e]]);
            o[e] = top + fy * (bot - top) + xe[e];
        }
        float4 ov = make_float4(o[0], o[1], o[2], o[3]);
        *(float4*)(op + y*256 + x4) = ov;
    }
}

extern "C" void kernel_launch(void* const* d_in, const int* in_sizes, int n_in,
                              void* d_out, int out_size, void* d_ws, size_t ws_size,
                              hipStream_t stream)
{
    const float* x   = (const float*)d_in[0];
    const float* f_w = (const float*)d_in[1];
    const float* f_b = (const float*)d_in[2];
    const float* g_w = (const float*)d_in[3];
    const float* g_b = (const float*)d_in[4];
    const float* h_w = (const float*)d_in[5];
    const float* h_b = (const float*)d_in[6];
    float* out = (float*)d_out;

    char* ws = (char*)d_ws;
    f16*   wf        = (f16*)ws;                              // 256 KB
    float* pooled_fg = (float*)(ws + (256<<10));              // 1 MB  [B][256][256]
    float* pooledT_h = (float*)(ws + (256<<10) + (1<<20));    // 1 MB  [B][256][256]
    float* attnout   = (float*)(ws + (256<<10) + (2<<20));    // 1 MB  [B][256][256]

    k_convert_w   <<<512, 256, 0, stream>>>(f_w, g_w, h_w, wf);
    k_pooled_conv <<<256, 1024, 0, stream>>>(x, wf, f_b, g_b, h_b, pooled_fg, pooledT_h);
    k_attn        <<<1024, 256, 0, stream>>>(pooled_fg, pooledT_h, attnout);
    k_upsample_add<<<1024, 256, 0, stream>>>(x, attnout, out);
}

// Round 5
// 293.713 us; speedup vs baseline: 1.0414x; 1.0082x over previous
//
#include <hip/hip_runtime.h>
#include <hip/hip_fp16.h>

typedef _Float16 f16;
typedef _Float16 f16x4_t __attribute__((ext_vector_type(4)));
typedef _Float16 f16x8_t __attribute__((ext_vector_type(8)));
typedef float    f32x4_t __attribute__((ext_vector_type(4)));

#define NB  4
#define NC  256
#define NH  256
#define NW  256

// ---------------- kernel 1: convert weights (f,g,h) to f16, row-major [cout][ch] ----
__global__ __launch_bounds__(256) void k_convert_w(
    const float* __restrict__ f_w, const float* __restrict__ g_w,
    const float* __restrict__ h_w, f16* __restrict__ wf)
{
    int id = blockIdx.x * 256 + threadIdx.x;   // 0 .. 131071  (512*256)
    int cout = id >> 8;
    float v;
    if (cout < 128)       v = f_w[id];
    else if (cout < 256)  v = g_w[id - 128*256];
    else                  v = h_w[id - 256*256];
    wf[id] = (f16)v;
}

// Raw barrier: drain own LDS ops, then s_barrier. NO vmcnt drain -> prefetch
// global loads (register-destined) stay in flight across the barrier; the
// compiler inserts counted vmcnt(N) at the registers' first use (T4 pattern).
__device__ __forceinline__ void bar_lds() {
    asm volatile("s_waitcnt lgkmcnt(0)" ::: "memory");
    __builtin_amdgcn_s_barrier();
}

// ---------------- kernel 2: fused conv1x1 (512 couts) + 16x16 maxpool ----------------
// 256 blocks x 1024 threads (16 waves, 4/SIMD), 4 windows/block, 32 stages of 32 pos.
// Wave w: 32 couts (n=2). Waves 0-7 = f,g (hi/lo 2-pass), waves 8-15 = h (1-pass).
// LDS identity layout (conflict-free reads), register-staged writes, raw barriers.
__global__ __launch_bounds__(1024, 4) void k_pooled_conv(
    const float* __restrict__ x, const f16* __restrict__ wf,
    const float* __restrict__ f_b, const float* __restrict__ g_b,
    const float* __restrict__ h_b,
    float* __restrict__ pooled_fg,   // [B][256][256]
    float* __restrict__ pooledT_h)   // [B][256][256]
{
    __shared__ __align__(16) char smem[65536];  // 2 buffers x (16KB hi + 16KB lo)

    const int t    = threadIdx.x;
    const int wave = t >> 6;
    const int lane = t & 63;
    const int l15  = lane & 15;
    const int lg   = lane >> 4;
    const bool isfg = (wave < 8);
    const int coutbase = isfg ? wave * 32 : 256 + (wave - 8) * 32;

    // ---- persistent weight fragments: 2 cout-frags x 8 k-steps (64 VGPR) ----
    f16x8_t bfrag[2][8];
    #pragma unroll
    for (int n = 0; n < 2; n++) {
        const f16* wr = wf + (coutbase + n*16 + l15) * 256 + lg*8;
        #pragma unroll
        for (int k = 0; k < 8; k++)
            bfrag[n][k] = *(const f16x8_t*)(wr + k*32);
    }
    float biasv[2];
    #pragma unroll
    for (int n = 0; n < 2; n++) {
        int c = coutbase + n*16 + l15;
        biasv[n] = (c < 128) ? f_b[c] : (c < 256) ? g_b[c - 128] : h_b[c - 256];
    }

    // ---- staging coords: thread owns 1 dx x 8 consecutive ch ----
    const int dx  = t & 15;
    const int dyl = (t >> 4) & 1;
    const int c8  = (t >> 5) * 8;     // 0..248
    const unsigned page = (unsigned)(dyl*8 + (c8 >> 5));
    const unsigned slot = (unsigned)(dx | (((c8 >> 3) & 3) << 4));
    const unsigned woff = (page << 10) + slot * 16u;

    const int bid   = blockIdx.x;
    const int b     = bid >> 6;
    const int wbase = bid * 4;
    const float* xb = x + (size_t)b * (256u * 65536u);

    float vmax[2] = {-3.0e38f, -3.0e38f};

    auto loadst = [&](int gsd, float* r) {
        int win = wbase + (gsd >> 3);
        int s   = gsd & 7;
        int wi = (win >> 4) & 15, wj = win & 15;
        const float* src = xb + (size_t)c8 * 65536u
                         + (unsigned)((wi*16 + s*2 + dyl) * 256 + wj*16 + dx);
        #pragma unroll
        for (int cc = 0; cc < 8; cc++)
            r[cc] = src[(unsigned)cc * 65536u];
    };
    auto writest = [&](const float* r, int buf) {
        char* base = smem + buf * 32768;
        f16x8_t hv, lv;
        #pragma unroll
        for (int cc = 0; cc < 8; cc++) {
            float v = r[cc];
            f16 h = (f16)v;
            hv[cc] = h;
            lv[cc] = (f16)(v - (float)h);
        }
        *(f16x8_t*)(base + woff)         = hv;
        *(f16x8_t*)(base + 16384 + woff) = lv;
    };
    auto mfmast = [&](int buf) {
        const char* base = smem + buf * 32768 + lane * 16;
        #pragma unroll
        for (int m = 0; m < 2; m++) {
            f32x4_t acc0 = {0.f,0.f,0.f,0.f}, acc1 = {0.f,0.f,0.f,0.f};
            #pragma unroll
            for (int k = 0; k < 8; k++) {
                const char* p = base + ((m*8 + k) << 10);
                f16x8_t ah = *(const f16x8_t*)p;
                acc0 = __builtin_amdgcn_mfma_f32_16x16x32_f16(ah, bfrag[0][k], acc0, 0,0,0);
                acc1 = __builtin_amdgcn_mfma_f32_16x16x32_f16(ah, bfrag[1][k], acc1, 0,0,0);
                if (isfg) {
                    f16x8_t al = *(const f16x8_t*)(p + 16384);
                    acc0 = __builtin_amdgcn_mfma_f32_16x16x32_f16(al, bfrag[0][k], acc0, 0,0,0);
                    acc1 = __builtin_amdgcn_mfma_f32_16x16x32_f16(al, bfrag[1][k], acc1, 0,0,0);
                }
            }
            #pragma unroll
            for (int r = 0; r < 4; r++) {
                vmax[0] = fmaxf(vmax[0], acc0[r]);
                vmax[1] = fmaxf(vmax[1], acc1[r]);
            }
        }
    };
    auto finalize = [&](int win) {
        int wn = win & 255;
        #pragma unroll
        for (int n = 0; n < 2; n++) {
            float v = vmax[n];
            v = fmaxf(v, __shfl_xor(v, 16, 64));
            v = fmaxf(v, __shfl_xor(v, 32, 64));
            if (lane < 16) {
                float val = v + biasv[n];
                int c = coutbase + n*16 + lane;
                if (isfg) pooled_fg[((b*256 + c)  << 8) + wn] = val;
                else      pooledT_h[((b*256 + wn) << 8) + (c - 256)] = val;
            }
            vmax[n] = -3.0e38f;
        }
    };

    // ---- pipeline: 32 global stages (4 windows x 8 stages of 2 rows) ----
    // Depth-2 register prefetch; ds-write one stage ahead; raw barriers only.
    float rA[8], rB[8];
    loadst(0, rA);
    loadst(1, rB);
    writest(rA, 0);      // compiler: vmcnt(8) wait (rB still in flight)
    bar_lds();

    #pragma unroll 1
    for (int gs = 0; gs < 32; gs += 2) {
        // stage gs: compute buf0
        if (gs + 2 < 32) loadst(gs + 2, rA);   // issue; rA regs free
        writest(rB, 1);                        // waits rB loads (counted vmcnt)
        mfmast(0);
        bar_lds();
        // stage gs+1: compute buf1
        if (gs + 3 < 32) loadst(gs + 3, rB);
        if (gs + 2 < 32) writest(rA, 0);
        mfmast(1);
        if ((gs & 7) == 6) finalize(wbase + (gs >> 3));
        bar_lds();
    }
}

// ---------------- kernel 3: dots + softmax + PV (all fp32) ----------------
__global__ __launch_bounds__(256) void k_attn(
    const float* __restrict__ pooled_fg, const float* __restrict__ pooledT_h,
    float* __restrict__ attnout)   // [B][256][256]
{
    __shared__ float red[4];
    __shared__ float p_lds[256];
    const int blk = blockIdx.x;
    const int b = blk >> 8;
    const int q = blk & 255;
    const int t = threadIdx.x;

    const float* fv = pooled_fg + ((b*256) << 8) + q;         // fv[c][q]
    const float* gv = pooled_fg + ((b*256 + 128) << 8) + t;   // gv[c][t]

    float s = 0.f;
    #pragma unroll 8
    for (int c = 0; c < 128; c++)
        s += fv[c << 8] * gv[c << 8];

    float m = s;
    #pragma unroll
    for (int o = 1; o < 64; o <<= 1) m = fmaxf(m, __shfl_xor(m, o, 64));
    if ((t & 63) == 0) red[t >> 6] = m;
    __syncthreads();
    m = fmaxf(fmaxf(red[0], red[1]), fmaxf(red[2], red[3]));
    __syncthreads();

    float p = expf(s - m);
    float sum = p;
    #pragma unroll
    for (int o = 1; o < 64; o <<= 1) sum += __shfl_xor(sum, o, 64);
    if ((t & 63) == 0) red[t >> 6] = sum;
    __syncthreads();
    sum = red[0] + red[1] + red[2] + red[3];
    p /= sum;
    p_lds[t] = p;
    __syncthreads();

    const float* hv = pooledT_h + (b << 16) + t;
    float acc = 0.f;
    #pragma unroll 8
    for (int k = 0; k < 256; k++)
        acc += p_lds[k] * hv[k << 8];
    attnout[((b*256 + t) << 8) + q] = acc;
}

// ---------------- kernel 4: bilinear 16x upsample (half-pixel, edge-clamped) + x ----
__global__ __launch_bounds__(256) void k_upsample_add(
    const float* __restrict__ x, const float* __restrict__ attnout,
    float* __restrict__ out)
{
    __shared__ float L[256];
    const int blk = blockIdx.x;            // b*256 + c
    const int t = threadIdx.x;
    L[t] = attnout[(blk << 8) + t];
    __syncthreads();
    const float* xp = x   + (size_t)blk * 65536;
    float*       op = out + (size_t)blk * 65536;

    const int x4 = (t & 63) << 2;
    const int yo = t >> 6;
    float fxv[4]; int x0v[4], x1v[4];
    #pragma unroll
    for (int e = 0; e < 4; e++) {
        float sx  = (x4 + e + 0.5f) * 0.0625f - 0.5f;
        float x0f = floorf(sx);
        fxv[e] = sx - x0f;
        int ix0 = (int)x0f;
        x0v[e] = min(15, max(0, ix0));
        x1v[e] = min(15, max(0, ix0 + 1));
    }
    for (int it = 0; it < 64; it++) {
        int y = it*4 + yo;
        float sy  = (y + 0.5f) * 0.0625f - 0.5f;
        float y0f = floorf(sy);
        float fy  = sy - y0f;
        int iy0 = (int)y0f;
        int y0 = min(15, max(0, iy0));
        int y1 = min(15, max(0, iy0 + 1));
        const float* Ly0 = L + y0*16;
        const float* Ly1 = L + y1*16;
        float4 xin = *(const float4*)(xp + y*256 + x4);
        float o[4]; const float* xe = (const float*)&xin;
        #pragma unroll
        for (int e = 0; e < 4; e++) {
            float top = Ly0[x0v[e]] + fxv[e] * (Ly0[x1v[e]] - Ly0[x0v[e]]);
            float bot = Ly1[x0v[e]] + fxv[e] * (Ly1[x1v[e]] - Ly1[x0v[e]]);
            o[e] = top + fy * (bot - top) + xe[e];
        }
        float4 ov = make_float4(o[0], o[1], o[2], o[3]);
        *(float4*)(op + y*256 + x4) = ov;
    }
}

extern "C" void kernel_launch(void* const* d_in, const int* in_sizes, int n_in,
                              void* d_out, int out_size, void* d_ws, size_t ws_size,
                              hipStream_t stream)
{
    const float* x   = (const float*)d_in[0];
    const float* f_w = (const float*)d_in[1];
    const float* f_b = (const float*)d_in[2];
    const float* g_w = (const float*)d_in[3];
    const float* g_b = (const float*)d_in[4];
    const float* h_w = (const float*)d_in[5];
    const float* h_b = (const float*)d_in[6];
    float* out = (float*)d_out;

    char* ws = (char*)d_ws;
    f16*   wf        = (f16*)ws;                              // 256 KB
    float* pooled_fg = (float*)(ws + (256<<10));              // 1 MB  [B][256][256]
    float* pooledT_h = (float*)(ws + (256<<10) + (1<<20));    // 1 MB  [B][256][256]
    float* attnout   = (float*)(ws + (256<<10) + (2<<20));    // 1 MB  [B][256][256]

    k_convert_w   <<<512, 256, 0, stream>>>(f_w, g_w, h_w, wf);
    k_pooled_conv <<<256, 1024, 0, stream>>>(x, wf, f_b, g_b, h_b, pooled_fg, pooledT_h);
    k_attn        <<<1024, 256, 0, stream>>>(pooled_fg, pooledT_h, attnout);
    k_upsample_add<<<1024, 256, 0, stream>>>(x, attnout, out);
}